// Round 11
// baseline (271.916 us; speedup 1.0000x reference)
//
#include <hip/hip_runtime.h>
#include <hip/hip_bf16.h>
#include <math.h>

#define N_NODES   50000
#define N_EDGES   1600000
#define IN_F      128
#define D_ATT     64
#define N_HEADS   8
#define D_HEAD    8
#define RSQRT8    0.35355339059327373f
#define EPS_SM    1e-16f
#define NEH       (N_EDGES * N_HEADS)      // 12.8M (edge,head)
#define LPAD      136                      // LDS row stride (bf16 elems)

// native clang vectors (required by nontemporal builtins / MFMA intrinsics)
typedef float f32x4 __attribute__((ext_vector_type(4)));
typedef short s16x8 __attribute__((ext_vector_type(8)));   // 8 bf16 (4 VGPRs)

__device__ inline unsigned short f2bf(float v) {
    __hip_bfloat16 b = __float2bfloat16(v);
    return *(unsigned short*)&b;
}
__device__ inline float bflo(unsigned u) { return __uint_as_float(u << 16); }
__device__ inline float bfhi(unsigned u) { return __uint_as_float(u & 0xffff0000u); }

// ---------------------------------------------------------------------------
// K1 (R6-PROVEN, best measured config): fused q/k/v projection via bf16 MFMA
// (16x16x32), f32 accumulate, per-matrix W staging (34.8 KB LDS -> 4 blk/CU).
// R8 single-stage null; R9 W-from-global regressed.  Zeroes ssum.
// Block = 64-node tile, 4 waves; wave w owns nodes [n0+16w, n0+16w+16).
// D = W x X^T: C/D col = lane&15 = node, row = (lane>>4)*4+reg = feat.
// ---------------------------------------------------------------------------
__global__ __launch_bounds__(256) void k_proj(
        const float* __restrict__ x,
        const float* __restrict__ Wq, const float* __restrict__ bq,
        const float* __restrict__ Wk, const float* __restrict__ bk,
        const float* __restrict__ Wv, const float* __restrict__ bv,
        unsigned short* __restrict__ qp, unsigned short* __restrict__ kp,
        float* __restrict__ vout, float* __restrict__ s) {
    __shared__ unsigned short Xb[64][LPAD];   // 17.4 KB  [node][k] bf16
    __shared__ unsigned short Wb[64][LPAD];   // 17.4 KB  [feat][k] bf16
    const int tid = threadIdx.x;
    const int n0  = blockIdx.x * 64;

    // ---- zero segment-sum table (grid-stride; 400K floats) ----
    {
        int nthr = gridDim.x * 256;
        for (int i = blockIdx.x * 256 + tid; i < N_NODES * N_HEADS; i += nthr)
            s[i] = 0.0f;
    }

    {   // ---- stage X tile as bf16: thread t -> node t>>2, quarter t&3 ----
        int node = tid >> 2;
        int q4   = tid & 3;
        int n    = n0 + node;
        unsigned short* dst = &Xb[node][q4 * 32];
        if (n < N_NODES) {
            const float4* xr = (const float4*)(x + (size_t)n * IN_F + q4 * 32);
#pragma unroll
            for (int i = 0; i < 8; ++i) {
                float4 v = xr[i];
                *(unsigned*)(dst + i * 4)     = ((unsigned)f2bf(v.y) << 16) | f2bf(v.x);
                *(unsigned*)(dst + i * 4 + 2) = ((unsigned)f2bf(v.w) << 16) | f2bf(v.z);
            }
        } else {
#pragma unroll
            for (int i = 0; i < 16; ++i) ((unsigned*)dst)[i] = 0u;
        }
    }

    const int wv   = tid >> 6;        // wave id -> node subtile
    const int ln   = tid & 63;
    const int lane = ln & 15;         // node (B col) AND feat (A row) index
    const int kgrp = ln >> 4;         // k-group / D-row group
    const int mynode = n0 + wv * 16 + lane;
    const int f0     = kgrp * 4;      // D rows = feats f0..f0+3 within tile

    const float* Wlist[3] = {Wq, Wk, Wv};
    const float* blist[3] = {bq, bk, bv};

    for (int mm = 0; mm < 3; ++mm) {
        __syncthreads();              // Xb ready / prev-mat reads done
        {   // ---- stage W tile as bf16: thread t -> feat t>>2, quarter t&3 ----
            int feat = tid >> 2;
            int q4   = tid & 3;
            const float4* wr = (const float4*)(Wlist[mm] + (size_t)feat * IN_F + q4 * 32);
            unsigned short* dst = &Wb[feat][q4 * 32];
#pragma unroll
            for (int i = 0; i < 8; ++i) {
                float4 v = wr[i];
                *(unsigned*)(dst + i * 4)     = ((unsigned)f2bf(v.y) << 16) | f2bf(v.x);
                *(unsigned*)(dst + i * 4 + 2) = ((unsigned)f2bf(v.w) << 16) | f2bf(v.z);
            }
        }
        __syncthreads();

        f32x4 acc[4];
#pragma unroll
        for (int ft = 0; ft < 4; ++ft) acc[ft] = (f32x4){0.f, 0.f, 0.f, 0.f};

#pragma unroll
        for (int ks = 0; ks < 4; ++ks) {
            int kof = ks * 32 + kgrp * 8;
            s16x8 xf = *(const s16x8*)&Xb[wv * 16 + lane][kof];
#pragma unroll
            for (int ft = 0; ft < 4; ++ft) {
                s16x8 wf = *(const s16x8*)&Wb[ft * 16 + lane][kof];
                acc[ft] = __builtin_amdgcn_mfma_f32_16x16x32_bf16(wf, xf, acc[ft], 0, 0, 0);
            }
        }

        if (mynode < N_NODES) {
            if (mm < 2) {
                unsigned short* dstp = (mm == 0 ? qp : kp) + (size_t)mynode * 64;
#pragma unroll
                for (int ft = 0; ft < 4; ++ft) {
                    int fb = ft * 16 + f0;
                    float4 bj = *(const float4*)&blist[mm][fb];
                    ushort4 o;
                    o.x = f2bf(acc[ft].x + bj.x);
                    o.y = f2bf(acc[ft].y + bj.y);
                    o.z = f2bf(acc[ft].z + bj.z);
                    o.w = f2bf(acc[ft].w + bj.w);
                    *(ushort4*)(dstp + fb) = o;
                }
            } else {
#pragma unroll
                for (int ft = 0; ft < 4; ++ft) {
                    int fb = ft * 16 + f0;
                    float4 bj = *(const float4*)&blist[mm][fb];
                    float vv[4] = {acc[ft].x + bj.x, acc[ft].y + bj.y,
                                   acc[ft].z + bj.z, acc[ft].w + bj.w};
#pragma unroll
                    for (int j = 0; j < 4; ++j) {
                        int f = fb + j;
                        vout[(size_t)mynode * 64 + (f & 7) * 8 + (f >> 3)] = vv[j];
                    }
                }
            }
        }
    }
}

// ---------------------------------------------------------------------------
// K2 (proven ~88 us): prods + exp + segment-sum. 8 threads/edge.
// prods store PLAIN (R10 win: L3 holds the producer->consumer round-trip).
// f32 atomicAdd fire-and-forget.  No max-subtraction (|logit| small).
// ---------------------------------------------------------------------------
__global__ void k_prods_exp(const int* __restrict__ e0, const int* __restrict__ e1,
                            const float* __restrict__ ea,
                            const unsigned short* __restrict__ qp,
                            const unsigned short* __restrict__ kp,
                            float* __restrict__ prods_out,
                            float* __restrict__ s) {
    int t = blockIdx.x * blockDim.x + threadIdx.x;
    if (t >= NEH) return;
    int e = t >> 3, h = t & 7;
    int src = e0[e];
    int dst = e1[e];
    float w = ea[e] * RSQRT8;
    uint4 qv = *(const uint4*)(qp + (size_t)src * 64 + h * 8);
    uint4 kv = *(const uint4*)(kp + (size_t)dst * 64 + h * 8);
    float dot = bflo(qv.x) * bflo(kv.x) + bfhi(qv.x) * bfhi(kv.x)
              + bflo(qv.y) * bflo(kv.y) + bfhi(qv.y) * bfhi(kv.y)
              + bflo(qv.z) * bflo(kv.z) + bfhi(qv.z) * bfhi(kv.z)
              + bflo(qv.w) * bflo(kv.w) + bfhi(qv.w) * bfhi(kv.w);
    float p = dot * w;
    prods_out[t] = p;                                // PLAIN: L3 keeps it for K3
    atomicAdd(&s[(size_t)dst * 8 + h], __expf(p));
}

// ---------------------------------------------------------------------------
// K2.5 (new, ~2-4 us): s[i] <- 1/(s[i]+eps), IN PLACE.  400K IEEE divides
// instead of 12.8M in K3.  K3's shape-invariant ~75 us is explained by
// 12.8M un-fast-math'd IEEE f32 div sequences (~12 issue-cyc each ~ 62 us
// of VALU); the reciprocal depends only on (node,head) so it hoists here.
// ---------------------------------------------------------------------------
__global__ void k_rcp(float* __restrict__ s) {
    int i = blockIdx.x * blockDim.x + threadIdx.x;
    if (i < N_NODES * N_HEADS)
        s[i] = 1.0f / (s[i] + EPS_SM);
}

// ---------------------------------------------------------------------------
// K3 v3: att = exp(prods) * rinv[dst,h]  (rinv = precomputed 1/(s+eps)).
// Same R6-proven f32x4 thread mapping; divide replaced by multiply ->
// per-thread VALU ~36 -> ~20 cyc, div pipeline pressure gone.
// Extra rounding vs reference (mul of rcp vs direct div): ~1 ulp = 1e-7.
// prods load PLAIN (L3-hot); att store NT (pure output).
// ---------------------------------------------------------------------------
__global__ void k_norm(const int* __restrict__ e1,
                       const float* __restrict__ prods,
                       float* __restrict__ att,
                       const float* __restrict__ rinv) {
    int i = blockIdx.x * blockDim.x + threadIdx.x;
    if (i >= NEH / 4) return;
    int e  = i >> 1;
    int h0 = (i & 1) * 4;
    int dst = e1[e];

    f32x4 pv = ((const f32x4*)prods)[i];             // PLAIN: L3 hit
    f32x4 rv = *(const f32x4*)(rinv + (size_t)dst * 8 + h0);

    f32x4 a;
    a.x = __expf(pv.x) * rv.x;
    a.y = __expf(pv.y) * rv.y;
    a.z = __expf(pv.z) * rv.z;
    a.w = __expf(pv.w) * rv.w;
    __builtin_nontemporal_store(a, &((f32x4*)att)[i]);
}

extern "C" void kernel_launch(void* const* d_in, const int* in_sizes, int n_in,
                              void* d_out, int out_size, void* d_ws, size_t ws_size,
                              hipStream_t stream) {
    const float* x  = (const float*)d_in[0];
    const float* Wq = (const float*)d_in[1];
    const float* bq = (const float*)d_in[2];
    const float* Wk = (const float*)d_in[3];
    const float* bk = (const float*)d_in[4];
    const float* Wv = (const float*)d_in[5];
    const float* bv = (const float*)d_in[6];
    const float* ea = (const float*)d_in[7];
    const int*   edge = (const int*)d_in[8];
    const int* e0 = edge;
    const int* e1 = edge + N_EDGES;

    float* out   = (float*)d_out;
    float* att   = out;                                  // (E, 8)
    float* vout  = att + (size_t)NEH;                    // (N, 8, 8)
    float* prods = vout + (size_t)N_NODES * D_ATT;       // (E, 8)

    unsigned short* qp = (unsigned short*)d_ws;          // (N, 64) bf16
    unsigned short* kp = qp + (size_t)N_NODES * D_ATT;   // (N, 64) bf16
    float* ssum = (float*)(kp + (size_t)N_NODES * D_ATT);// (N, 8) f32

    const int B = 256;
    int nTiles = (N_NODES + 63) / 64;
    k_proj<<<nTiles, 256, 0, stream>>>(x, Wq, bq, Wk, bk, Wv, bv,
                                       qp, kp, vout, ssum);

    int nEH = NEH;
    k_prods_exp<<<(nEH + B - 1) / B, B, 0, stream>>>(e0, e1, ea, qp, kp,
                                                     prods, ssum);

    int nS = N_NODES * N_HEADS;
    k_rcp<<<(nS + B - 1) / B, B, 0, stream>>>(ssum);

    int nV = NEH / 4;
    k_norm<<<(nV + B - 1) / B, B, 0, stream>>>(e1, prods, att, ssum);
}

// Round 12
// 267.376 us; speedup vs baseline: 1.0170x; 1.0170x over previous
//
#include <hip/hip_runtime.h>
#include <hip/hip_bf16.h>
#include <math.h>

#define N_NODES   50000
#define N_EDGES   1600000
#define IN_F      128
#define D_ATT     64
#define N_HEADS   8
#define D_HEAD    8
#define RSQRT8    0.35355339059327373f
#define EPS_SM    1e-16f
#define NEH       (N_EDGES * N_HEADS)      // 12.8M (edge,head)
#define LPAD      136                      // LDS row stride (bf16 elems)

// native clang vectors (required by nontemporal builtins / MFMA intrinsics)
typedef float f32x4 __attribute__((ext_vector_type(4)));
typedef short s16x8 __attribute__((ext_vector_type(8)));   // 8 bf16 (4 VGPRs)

__device__ inline unsigned short f2bf(float v) {
    __hip_bfloat16 b = __float2bfloat16(v);
    return *(unsigned short*)&b;
}
__device__ inline float bflo(unsigned u) { return __uint_as_float(u << 16); }
__device__ inline float bfhi(unsigned u) { return __uint_as_float(u & 0xffff0000u); }

// ---------------------------------------------------------------------------
// K1 (R6-PROVEN): fused q/k/v projection via bf16 MFMA (16x16x32), f32
// accumulate, per-matrix W staging (34.8 KB LDS -> 4 blk/CU).  Zeroes ssum.
// Block = 64-node tile, 4 waves; wave w owns nodes [n0+16w, n0+16w+16).
// D = W x X^T: C/D col = lane&15 = node, row = (lane>>4)*4+reg = feat.
// ---------------------------------------------------------------------------
__global__ __launch_bounds__(256) void k_proj(
        const float* __restrict__ x,
        const float* __restrict__ Wq, const float* __restrict__ bq,
        const float* __restrict__ Wk, const float* __restrict__ bk,
        const float* __restrict__ Wv, const float* __restrict__ bv,
        unsigned short* __restrict__ qp, unsigned short* __restrict__ kp,
        float* __restrict__ vout, float* __restrict__ s) {
    __shared__ unsigned short Xb[64][LPAD];   // 17.4 KB  [node][k] bf16
    __shared__ unsigned short Wb[64][LPAD];   // 17.4 KB  [feat][k] bf16
    const int tid = threadIdx.x;
    const int n0  = blockIdx.x * 64;

    // ---- zero segment-sum table (grid-stride; 400K floats) ----
    {
        int nthr = gridDim.x * 256;
        for (int i = blockIdx.x * 256 + tid; i < N_NODES * N_HEADS; i += nthr)
            s[i] = 0.0f;
    }

    {   // ---- stage X tile as bf16: thread t -> node t>>2, quarter t&3 ----
        int node = tid >> 2;
        int q4   = tid & 3;
        int n    = n0 + node;
        unsigned short* dst = &Xb[node][q4 * 32];
        if (n < N_NODES) {
            const float4* xr = (const float4*)(x + (size_t)n * IN_F + q4 * 32);
#pragma unroll
            for (int i = 0; i < 8; ++i) {
                float4 v = xr[i];
                *(unsigned*)(dst + i * 4)     = ((unsigned)f2bf(v.y) << 16) | f2bf(v.x);
                *(unsigned*)(dst + i * 4 + 2) = ((unsigned)f2bf(v.w) << 16) | f2bf(v.z);
            }
        } else {
#pragma unroll
            for (int i = 0; i < 16; ++i) ((unsigned*)dst)[i] = 0u;
        }
    }

    const int wv   = tid >> 6;        // wave id -> node subtile
    const int ln   = tid & 63;
    const int lane = ln & 15;         // node (B col) AND feat (A row) index
    const int kgrp = ln >> 4;         // k-group / D-row group
    const int mynode = n0 + wv * 16 + lane;
    const int f0     = kgrp * 4;      // D rows = feats f0..f0+3 within tile

    const float* Wlist[3] = {Wq, Wk, Wv};
    const float* blist[3] = {bq, bk, bv};

    for (int mm = 0; mm < 3; ++mm) {
        __syncthreads();              // Xb ready / prev-mat reads done
        {   // ---- stage W tile as bf16: thread t -> feat t>>2, quarter t&3 ----
            int feat = tid >> 2;
            int q4   = tid & 3;
            const float4* wr = (const float4*)(Wlist[mm] + (size_t)feat * IN_F + q4 * 32);
            unsigned short* dst = &Wb[feat][q4 * 32];
#pragma unroll
            for (int i = 0; i < 8; ++i) {
                float4 v = wr[i];
                *(unsigned*)(dst + i * 4)     = ((unsigned)f2bf(v.y) << 16) | f2bf(v.x);
                *(unsigned*)(dst + i * 4 + 2) = ((unsigned)f2bf(v.w) << 16) | f2bf(v.z);
            }
        }
        __syncthreads();

        f32x4 acc[4];
#pragma unroll
        for (int ft = 0; ft < 4; ++ft) acc[ft] = (f32x4){0.f, 0.f, 0.f, 0.f};

#pragma unroll
        for (int ks = 0; ks < 4; ++ks) {
            int kof = ks * 32 + kgrp * 8;
            s16x8 xf = *(const s16x8*)&Xb[wv * 16 + lane][kof];
#pragma unroll
            for (int ft = 0; ft < 4; ++ft) {
                s16x8 wf = *(const s16x8*)&Wb[ft * 16 + lane][kof];
                acc[ft] = __builtin_amdgcn_mfma_f32_16x16x32_bf16(wf, xf, acc[ft], 0, 0, 0);
            }
        }

        if (mynode < N_NODES) {
            if (mm < 2) {
                unsigned short* dstp = (mm == 0 ? qp : kp) + (size_t)mynode * 64;
#pragma unroll
                for (int ft = 0; ft < 4; ++ft) {
                    int fb = ft * 16 + f0;
                    float4 bj = *(const float4*)&blist[mm][fb];
                    ushort4 o;
                    o.x = f2bf(acc[ft].x + bj.x);
                    o.y = f2bf(acc[ft].y + bj.y);
                    o.z = f2bf(acc[ft].z + bj.z);
                    o.w = f2bf(acc[ft].w + bj.w);
                    *(ushort4*)(dstp + fb) = o;
                }
            } else {
#pragma unroll
                for (int ft = 0; ft < 4; ++ft) {
                    int fb = ft * 16 + f0;
                    float4 bj = *(const float4*)&blist[mm][fb];
                    float vv[4] = {acc[ft].x + bj.x, acc[ft].y + bj.y,
                                   acc[ft].z + bj.z, acc[ft].w + bj.w};
#pragma unroll
                    for (int j = 0; j < 4; ++j) {
                        int f = fb + j;
                        vout[(size_t)mynode * 64 + (f & 7) * 8 + (f >> 3)] = vv[j];
                    }
                }
            }
        }
    }
}

// ---------------------------------------------------------------------------
// K2 (proven ~88 us): prods + exp + segment-sum. 8 threads/edge (one per
// head); each lane reads a contiguous 16 B bf16 q fragment + 16 B k fragment
// (an edge's 8 lanes cover its two 128 B rows exactly -> line-minimal
// gather).  f32 atomicAdd fire-and-forget.  prods store PLAIN (R10 win:
// prods is a producer->consumer buffer; L3 holds the round-trip).
// No max-subtraction: |logit| <~ 1 (verified absmax history).
// ---------------------------------------------------------------------------
__global__ void k_prods_exp(const int* __restrict__ e0, const int* __restrict__ e1,
                            const float* __restrict__ ea,
                            const unsigned short* __restrict__ qp,
                            const unsigned short* __restrict__ kp,
                            float* __restrict__ prods_out,
                            float* __restrict__ s) {
    int t = blockIdx.x * blockDim.x + threadIdx.x;
    if (t >= NEH) return;
    int e = t >> 3, h = t & 7;
    int src = e0[e];
    int dst = e1[e];
    float w = ea[e] * RSQRT8;
    uint4 qv = *(const uint4*)(qp + (size_t)src * 64 + h * 8);
    uint4 kv = *(const uint4*)(kp + (size_t)dst * 64 + h * 8);
    float dot = bflo(qv.x) * bflo(kv.x) + bfhi(qv.x) * bfhi(kv.x)
              + bflo(qv.y) * bflo(kv.y) + bfhi(qv.y) * bfhi(kv.y)
              + bflo(qv.z) * bflo(kv.z) + bfhi(qv.z) * bfhi(kv.z)
              + bflo(qv.w) * bflo(kv.w) + bfhi(qv.w) * bfhi(kv.w);
    float p = dot * w;
    prods_out[t] = p;                                // PLAIN: L3 keeps it for K3
    atomicAdd(&s[(size_t)dst * 8 + h], __expf(p));
}

// ---------------------------------------------------------------------------
// K3 (R10-PROVEN): att = exp(prods) / (s[dst,h] + eps), f32x4.
// Thread i handles t = 4i..4i+3: e = i>>1, h0 = 4*(i&1) -> one aligned 16-B
// s gather from the L2-hot table.  prods load PLAIN (L3-hot after K2);
// att store NT (pure output, never re-read).
// (R11 falsified the div-bound theory: rcp-hoist + mul was +4 us.)
// ---------------------------------------------------------------------------
__global__ void k_norm(const int* __restrict__ e1,
                       const float* __restrict__ prods,
                       float* __restrict__ att,
                       const float* __restrict__ s) {
    int i = blockIdx.x * blockDim.x + threadIdx.x;
    if (i >= NEH / 4) return;
    int e  = i >> 1;
    int h0 = (i & 1) * 4;
    int dst = e1[e];

    f32x4 pv = ((const f32x4*)prods)[i];             // PLAIN: L3 hit
    f32x4 sv = *(const f32x4*)(s + (size_t)dst * 8 + h0);

    f32x4 a;
    a.x = __expf(pv.x) / (sv.x + EPS_SM);
    a.y = __expf(pv.y) / (sv.y + EPS_SM);
    a.z = __expf(pv.z) / (sv.z + EPS_SM);
    a.w = __expf(pv.w) / (sv.w + EPS_SM);
    __builtin_nontemporal_store(a, &((f32x4*)att)[i]);
}

extern "C" void kernel_launch(void* const* d_in, const int* in_sizes, int n_in,
                              void* d_out, int out_size, void* d_ws, size_t ws_size,
                              hipStream_t stream) {
    const float* x  = (const float*)d_in[0];
    const float* Wq = (const float*)d_in[1];
    const float* bq = (const float*)d_in[2];
    const float* Wk = (const float*)d_in[3];
    const float* bk = (const float*)d_in[4];
    const float* Wv = (const float*)d_in[5];
    const float* bv = (const float*)d_in[6];
    const float* ea = (const float*)d_in[7];
    const int*   edge = (const int*)d_in[8];
    const int* e0 = edge;
    const int* e1 = edge + N_EDGES;

    float* out   = (float*)d_out;
    float* att   = out;                                  // (E, 8)
    float* vout  = att + (size_t)NEH;                    // (N, 8, 8)
    float* prods = vout + (size_t)N_NODES * D_ATT;       // (E, 8)

    unsigned short* qp = (unsigned short*)d_ws;          // (N, 64) bf16
    unsigned short* kp = qp + (size_t)N_NODES * D_ATT;   // (N, 64) bf16
    float* ssum = (float*)(kp + (size_t)N_NODES * D_ATT);// (N, 8) f32

    const int B = 256;
    int nTiles = (N_NODES + 63) / 64;
    k_proj<<<nTiles, 256, 0, stream>>>(x, Wq, bq, Wk, bk, Wv, bv,
                                       qp, kp, vout, ssum);

    int nEH = NEH;
    k_prods_exp<<<(nEH + B - 1) / B, B, 0, stream>>>(e0, e1, ea, qp, kp,
                                                     prods, ssum);

    int nV = NEH / 4;
    k_norm<<<(nV + B - 1) / B, B, 0, stream>>>(e1, prods, att, ssum);
}